// Round 10
// baseline (639.916 us; speedup 1.0000x reference)
//
#include <hip/hip_runtime.h>
#include <hip/hip_fp16.h>
#include <cstdint>
#include <cstddef>

#define NN 50000
#define NE 800000
#define HID 64
#define INF_ 128
#define BN_EPS 1e-5f
#define NGRP (NN / 8)        // 6250 node-octets for fp16 props
#define NG16 (NN / 16)       // 3125 node-16-groups for fp8 APPNP
#define SCAN_B 196           // ceil(50000/256)

typedef float floatx2 __attribute__((ext_vector_type(2)));

// ---------------- fp16 pack/unpack ----------------
__device__ __forceinline__ float4 h8_to_f4(float2 raw) {
    union { float f; __half2 h; } ua, ub;
    ua.f = raw.x; ub.f = raw.y;
    float2 fa = __half22float2(ua.h), fb = __half22float2(ub.h);
    return make_float4(fa.x, fa.y, fb.x, fb.y);
}
__device__ __forceinline__ float2 f4_to_h8(float4 v) {
    union { float f; __half2 h; } ua, ub;
    ua.h = __float22half2_rn(make_float2(v.x, v.y));
    ub.h = __float22half2_rn(make_float2(v.z, v.w));
    return make_float2(ua.f, ub.f);
}
struct f8 { float v[8]; };
__device__ __forceinline__ f8 h16_to_f8(float4 raw) {
    f8 r;
    union { float f; __half2 h; } u;
    float2 a;
    u.f = raw.x; a = __half22float2(u.h); r.v[0] = a.x; r.v[1] = a.y;
    u.f = raw.y; a = __half22float2(u.h); r.v[2] = a.x; r.v[3] = a.y;
    u.f = raw.z; a = __half22float2(u.h); r.v[4] = a.x; r.v[5] = a.y;
    u.f = raw.w; a = __half22float2(u.h); r.v[6] = a.x; r.v[7] = a.y;
    return r;
}
__device__ __forceinline__ float4 f8_to_h16(const f8& s) {
    union { float f; __half2 h; } u;
    float4 o;
    u.h = __float22half2_rn(make_float2(s.v[0], s.v[1])); o.x = u.f;
    u.h = __float22half2_rn(make_float2(s.v[2], s.v[3])); o.y = u.f;
    u.h = __float22half2_rn(make_float2(s.v[4], s.v[5])); o.z = u.f;
    u.h = __float22half2_rn(make_float2(s.v[6], s.v[7])); o.w = u.f;
    return o;
}

// ---------------- fp8 e4m3 (OCP, gfx950 HW cvt) pack/unpack ----------------
__device__ __forceinline__ void fp8x8_to_f(unsigned lo, unsigned hi, float out[8]) {
    floatx2 a = __builtin_amdgcn_cvt_pk_f32_fp8((int)lo, false);
    floatx2 b = __builtin_amdgcn_cvt_pk_f32_fp8((int)lo, true);
    floatx2 c = __builtin_amdgcn_cvt_pk_f32_fp8((int)hi, false);
    floatx2 d = __builtin_amdgcn_cvt_pk_f32_fp8((int)hi, true);
    out[0] = a[0]; out[1] = a[1]; out[2] = b[0]; out[3] = b[1];
    out[4] = c[0]; out[5] = c[1]; out[6] = d[0]; out[7] = d[1];
}
__device__ __forceinline__ void fp8x16_to_f(uint4 r, float out[16]) {
    fp8x8_to_f(r.x, r.y, out);
    fp8x8_to_f(r.z, r.w, out + 8);
}
__device__ __forceinline__ uint2 f_to_fp8x8(const float v[8]) {
    int w0 = __builtin_amdgcn_cvt_pk_fp8_f32(v[0], v[1], 0, false);
    w0 = __builtin_amdgcn_cvt_pk_fp8_f32(v[2], v[3], w0, true);
    int w1 = __builtin_amdgcn_cvt_pk_fp8_f32(v[4], v[5], 0, false);
    w1 = __builtin_amdgcn_cvt_pk_fp8_f32(v[6], v[7], w1, true);
    uint2 o; o.x = (unsigned)w0; o.y = (unsigned)w1;
    return o;
}
__device__ __forceinline__ uint4 f_to_fp8x16(const float v[16]) {
    uint2 a = f_to_fp8x8(v), b = f_to_fp8x8(v + 8);
    uint4 o; o.x = a.x; o.y = a.y; o.z = b.x; o.w = b.y;
    return o;
}

// ---------------- graph prep ----------------

__global__ void count_k(const int* __restrict__ dst, int* __restrict__ cnt) {
    int e = blockIdx.x * blockDim.x + threadIdx.x;
    if (e < NE) atomicAdd(&cnt[dst[e]], 1);
}

__global__ void dinv_k(const int* __restrict__ cnt, float* __restrict__ dinv) {
    int n = blockIdx.x * blockDim.x + threadIdx.x;
    if (n < NN) dinv[n] = rsqrtf((float)(cnt[n] + 1));   // +1 self-loop
}

// parallel scan of PADDED degrees ((deg+7)&~7) -> offs; 3 kernels
__global__ void scan1_k(const int* __restrict__ cnt, int* __restrict__ offs,
                        int* __restrict__ bsum) {
    __shared__ int sh[256];
    int t = threadIdx.x, i = blockIdx.x * 256 + t;
    int v = (i < NN) ? ((cnt[i] + 7) & ~7) : 0;
    sh[t] = v;
    __syncthreads();
    for (int d = 1; d < 256; d <<= 1) {
        int u = (t >= d) ? sh[t - d] : 0;
        __syncthreads();
        sh[t] += u;
        __syncthreads();
    }
    if (i < NN) offs[i] = sh[t] - v;
    if (t == 255) bsum[blockIdx.x] = sh[255];
}

__global__ void scan2_k(const int* __restrict__ bsum, int* __restrict__ bpre,
                        int* __restrict__ offs) {
    __shared__ int sh[256];
    int t = threadIdx.x;
    int v = (t < SCAN_B) ? bsum[t] : 0;
    sh[t] = v;
    __syncthreads();
    for (int d = 1; d < 256; d <<= 1) {
        int u = (t >= d) ? sh[t - d] : 0;
        __syncthreads();
        sh[t] += u;
        __syncthreads();
    }
    bpre[t] = sh[t] - v;
    if (t == 255) offs[NN] = sh[255];
}

__global__ void scan3_k(int* __restrict__ offs, const int* __restrict__ bpre) {
    int i = blockIdx.x * blockDim.x + threadIdx.x;
    if (i < NN) offs[i] += bpre[i >> 8];
}

__global__ void pad_k(const int* __restrict__ cnt, const int* __restrict__ offs,
                      int2* __restrict__ edge2) {
    int n = blockIdx.x * blockDim.x + threadIdx.x;
    if (n >= NN) return;
    int e = offs[n] + cnt[n], e1 = offs[n + 1];
    for (; e < e1; ++e) edge2[e] = make_int2(0, 0);   // w = 0.0f -> row 0, hot line
}

__global__ void scatter_k(const int* __restrict__ src, const int* __restrict__ dst,
                          const int* __restrict__ offs, int* __restrict__ cursor,
                          const float* __restrict__ dinv,
                          int2* __restrict__ edge2) {
    int e = blockIdx.x * blockDim.x + threadIdx.x;
    if (e < NE) {
        int s = src[e], d = dst[e];
        int pos = offs[d] + atomicAdd(&cursor[d], 1);
        edge2[pos] = make_int2(s, __float_as_int(dinv[s] * dinv[d]));
    }
}

// ---------------- dense matmul: Y[N,64] = X[N,K] @ W[K,64], fp16 out --------
template <int K, bool HIN>
__global__ __launch_bounds__(256) void mm_k(const void* __restrict__ Xv,
                                            const float* __restrict__ W,
                                            float2* __restrict__ Y) {
    const int t = threadIdx.x;
    const int n0 = blockIdx.x * 64;
    const int r0 = (t >> 4) << 2;
    const int c0 = (t & 15) << 2;

    int r[4];
#pragma unroll
    for (int j = 0; j < 4; ++j) {
        int rr = n0 + r0 + j;
        r[j] = rr < NN ? rr : NN - 1;
    }
    const float4* Xr4[4];
    const float2* Xr2[4];
#pragma unroll
    for (int j = 0; j < 4; ++j) {
        if (HIN) Xr2[j] = (const float2*)Xv + (size_t)r[j] * (K / 4);
        else     Xr4[j] = (const float4*)Xv + (size_t)r[j] * (K / 4);
    }

    float acc[4][4];
#pragma unroll
    for (int j = 0; j < 4; ++j)
#pragma unroll
        for (int c = 0; c < 4; ++c) acc[j][c] = 0.f;

#pragma unroll 4
    for (int kq = 0; kq < K / 4; ++kq) {
        float4 xv[4];
#pragma unroll
        for (int j = 0; j < 4; ++j)
            xv[j] = HIN ? h8_to_f4(Xr2[j][kq]) : Xr4[j][kq];
        float4 wv[4];
#pragma unroll
        for (int i = 0; i < 4; ++i)
            wv[i] = *(const float4*)(W + (size_t)(kq * 4 + i) * 64 + c0);
#pragma unroll
        for (int j = 0; j < 4; ++j) {
            acc[j][0] = fmaf(xv[j].x, wv[0].x, acc[j][0]);
            acc[j][1] = fmaf(xv[j].x, wv[0].y, acc[j][1]);
            acc[j][2] = fmaf(xv[j].x, wv[0].z, acc[j][2]);
            acc[j][3] = fmaf(xv[j].x, wv[0].w, acc[j][3]);
            acc[j][0] = fmaf(xv[j].y, wv[1].x, acc[j][0]);
            acc[j][1] = fmaf(xv[j].y, wv[1].y, acc[j][1]);
            acc[j][2] = fmaf(xv[j].y, wv[1].z, acc[j][2]);
            acc[j][3] = fmaf(xv[j].y, wv[1].w, acc[j][3]);
            acc[j][0] = fmaf(xv[j].z, wv[2].x, acc[j][0]);
            acc[j][1] = fmaf(xv[j].z, wv[2].y, acc[j][1]);
            acc[j][2] = fmaf(xv[j].z, wv[2].z, acc[j][2]);
            acc[j][3] = fmaf(xv[j].z, wv[2].w, acc[j][3]);
            acc[j][0] = fmaf(xv[j].w, wv[3].x, acc[j][0]);
            acc[j][1] = fmaf(xv[j].w, wv[3].y, acc[j][1]);
            acc[j][2] = fmaf(xv[j].w, wv[3].z, acc[j][2]);
            acc[j][3] = fmaf(xv[j].w, wv[3].w, acc[j][3]);
        }
    }

#pragma unroll
    for (int j = 0; j < 4; ++j) {
        int rr = n0 + r0 + j;
        if (rr < NN)
            Y[(size_t)rr * 16 + (t & 15)] =
                f4_to_h8(make_float4(acc[j][0], acc[j][1], acc[j][2], acc[j][3]));
    }
}

// ---- fp16 propagate core: software-pipelined, 8 rows/gather-batch ---------
// lane = slot*8 + fl; slot in [0,8), fl in [0,8). slotbase = lane & 56.
// Pipeline: batch i consumed while batch i+1's gathers are in flight;
// edge data prefetched 2 batches ahead so address shfl never drains gathers.
__device__ __forceinline__ void prop_gather8(const float4* __restrict__ X4,
                                             const int2* __restrict__ E,
                                             int e0, int e1, int fl, int slotbase,
                                             float acc[8], float acc2[8]) {
    if (e0 >= e1) return;
    int2 d0 = E[e0 + fl];
    int srcs[8]; float ws[8];
#pragma unroll
    for (int i = 0; i < 8; ++i) {
        srcs[i] = __shfl(d0.x, slotbase + i, 64);
        ws[i]   = __shfl(__int_as_float(d0.y), slotbase + i, 64);
    }
    int2 d1;
    if (e0 + 8 < e1) d1 = E[e0 + 8 + fl];     // edge prefetch (issued pre-gather)
    float4 rr[8];
#pragma unroll
    for (int i = 0; i < 8; ++i) rr[i] = X4[(size_t)srcs[i] * 8 + fl];

    for (int e = e0; e < e1; ) {
        int en = e + 8;
        float4 rn[8]; float wn[8];
        if (en < e1) {
            int sn[8];
#pragma unroll
            for (int i = 0; i < 8; ++i) {
                sn[i] = __shfl(d1.x, slotbase + i, 64);
                wn[i] = __shfl(__int_as_float(d1.y), slotbase + i, 64);
            }
            if (en + 8 < e1) d1 = E[en + 8 + fl];
#pragma unroll
            for (int i = 0; i < 8; ++i) rn[i] = X4[(size_t)sn[i] * 8 + fl];
        }
#pragma unroll
        for (int i = 0; i < 8; ++i) {
            f8 x = h16_to_f8(rr[i]);
            float* a = (i & 1) ? acc2 : acc;
#pragma unroll
            for (int j = 0; j < 8; ++j)
                a[j] = fmaf(ws[i], x.v[j], a[j]);
        }
        e = en;
        if (e < e1) {
#pragma unroll
            for (int i = 0; i < 8; ++i) { rr[i] = rn[i]; ws[i] = wn[i]; }
        }
    }
}

// ---------------- propagate + bias + BN-stats (fp16 in, fp16 out) ----------
// __launch_bounds__(256,2): ~256-VGPR cap so the 2x8-row gather pipeline stays
// in registers (64-reg default serialized gathers to 1 in flight -> R2..R9 wall)
__global__ __launch_bounds__(256, 2) void prop_stats_k(
        const float4* __restrict__ X4, const int* __restrict__ offs,
        const int2* __restrict__ edge2, const float* __restrict__ dinv,
        const float* __restrict__ bias, float4* __restrict__ Y4,
        float* __restrict__ stats) {
    const int lane = threadIdx.x & 63;
    const int wave = threadIdx.x >> 6;
    const int slot = lane >> 3;
    const int fl = lane & 7;
    const int slotbase = lane & 56;
    const int wid = blockIdx.x * 4 + wave;
    const int nw = gridDim.x * 4;

    float bias8[8];
    {
        float4 b0 = ((const float4*)bias)[fl * 2];
        float4 b1 = ((const float4*)bias)[fl * 2 + 1];
        bias8[0] = b0.x; bias8[1] = b0.y; bias8[2] = b0.z; bias8[3] = b0.w;
        bias8[4] = b1.x; bias8[5] = b1.y; bias8[6] = b1.z; bias8[7] = b1.w;
    }

    float s1[8], s2[8];
#pragma unroll
    for (int j = 0; j < 8; ++j) { s1[j] = 0.f; s2[j] = 0.f; }

    for (int g = wid; g < NGRP; g += nw) {
        int n = g * 8 + slot;
        float dn = dinv[n];
        float dd = dn * dn;
        f8 self = h16_to_f8(X4[(size_t)n * 8 + fl]);
        float acc[8], acc2[8];
#pragma unroll
        for (int j = 0; j < 8; ++j) { acc[j] = dd * self.v[j]; acc2[j] = 0.f; }
        int e0 = offs[n], e1 = offs[n + 1];
        prop_gather8(X4, edge2, e0, e1, fl, slotbase, acc, acc2);
        f8 o;
#pragma unroll
        for (int j = 0; j < 8; ++j) {
            float a = acc[j] + acc2[j] + bias8[j];
            o.v[j] = a;
            s1[j] += a;
            s2[j] = fmaf(a, a, s2[j]);
        }
        Y4[(size_t)n * 8 + fl] = f8_to_h16(o);
    }

    // reduce across the 8 slots (lanes differing in bits 3,4,5)
#pragma unroll
    for (int m = 8; m <= 32; m <<= 1) {
#pragma unroll
        for (int j = 0; j < 8; ++j) {
            s1[j] += __shfl_xor(s1[j], m, 64);
            s2[j] += __shfl_xor(s2[j], m, 64);
        }
    }

    __shared__ float red[4][8][16];
    if (lane < 8) {
#pragma unroll
        for (int j = 0; j < 8; ++j) {
            red[wave][lane][j] = s1[j];
            red[wave][lane][8 + j] = s2[j];
        }
    }
    __syncthreads();
    int t = threadIdx.x;
    if (t < 128) {
        int j = t & 63;            // feature index
        int isq = t >> 6;          // 0 = sum, 1 = sumsq
        int fli = j >> 3, c = (j & 7) + isq * 8;
        float a = red[0][fli][c] + red[1][fli][c] + red[2][fli][c] + red[3][fli][c];
        atomicAdd(&stats[isq * 64 + j], a);
    }
}

// ---------------- batchnorm + relu: fp16 in -> fp16 out ----------------
__global__ void bn_relu_k(const float4* __restrict__ Y4, const float* __restrict__ stats,
                          const float* __restrict__ g, const float* __restrict__ be,
                          float4* __restrict__ H4) {
    int i = blockIdx.x * blockDim.x + threadIdx.x;
    if (i >= NN * 8) return;
    int fg = i & 7;
    const float invN = 1.f / (float)NN;
    float4 sm0 = ((const float4*)stats)[fg * 2];
    float4 sm1 = ((const float4*)stats)[fg * 2 + 1];
    float4 sq0 = ((const float4*)(stats + 64))[fg * 2];
    float4 sq1 = ((const float4*)(stats + 64))[fg * 2 + 1];
    float4 gv0 = ((const float4*)g)[fg * 2];
    float4 gv1 = ((const float4*)g)[fg * 2 + 1];
    float4 bv0 = ((const float4*)be)[fg * 2];
    float4 bv1 = ((const float4*)be)[fg * 2 + 1];
    float sm[8] = { sm0.x, sm0.y, sm0.z, sm0.w, sm1.x, sm1.y, sm1.z, sm1.w };
    float sq[8] = { sq0.x, sq0.y, sq0.z, sq0.w, sq1.x, sq1.y, sq1.z, sq1.w };
    float gv[8] = { gv0.x, gv0.y, gv0.z, gv0.w, gv1.x, gv1.y, gv1.z, gv1.w };
    float bv[8] = { bv0.x, bv0.y, bv0.z, bv0.w, bv1.x, bv1.y, bv1.z, bv1.w };
    f8 y = h16_to_f8(Y4[i]);
    f8 o;
#pragma unroll
    for (int j = 0; j < 8; ++j) {
        float m = sm[j] * invN;
        float v = sq[j] * invN - m * m;
        float val = fmaf(gv[j] * rsqrtf(v + BN_EPS), y.v[j] - m, bv[j]);
        o.v[j] = val > 0.f ? val : 0.f;
    }
    H4[i] = f8_to_h16(o);
}

// ---------------- fp16 -> fp8 row conversion ----------------
__global__ void cvt16to8_k(const float4* __restrict__ H4, uint2* __restrict__ X8) {
    int i = blockIdx.x * blockDim.x + threadIdx.x;
    if (i >= NN * 8) return;
    f8 v = h16_to_f8(H4[i]);
    X8[i] = f_to_fp8x8(v.v);
}

// ---- fp8 APPNP: 16 nodes/wave, pipelined 8x16-row gathers -----------------
// lane = slot*4 + fl; slot in [0,16), fl in [0,4) -> feats [fl*16, fl*16+16)
template <bool OUT16>
__global__ __launch_bounds__(256, 2) void appnp8_k(
        const uint4* __restrict__ X8, const float4* __restrict__ H04,
        const int* __restrict__ offs, const int2* __restrict__ edge2,
        const float* __restrict__ dinv,
        uint4* __restrict__ Y8, float4* __restrict__ Y16) {
    const int lane = threadIdx.x & 63;
    const int wave = threadIdx.x >> 6;
    const int slot = lane >> 2;
    const int fl = lane & 3;
    const int quadbase = lane & 60;
    const int wid = blockIdx.x * 4 + wave;
    if (wid >= NG16) return;
    int n = wid * 16 + slot;
    float dn = dinv[n];
    float dd = dn * dn;
    float acc[16];
    {
        float self[16];
        fp8x16_to_f(X8[(size_t)n * 4 + fl], self);
#pragma unroll
        for (int j = 0; j < 16; ++j) acc[j] = dd * self[j];
    }
    int e0 = offs[n], e1 = offs[n + 1];
    if (e0 < e1) {
        int4 d = ((const int4*)(edge2 + e0))[fl];   // 2 edges per lane
        int srcs[8]; float ws[8];
#pragma unroll
        for (int k = 0; k < 8; ++k) {
            int sl = quadbase + (k >> 1);
            srcs[k] = __shfl((k & 1) ? d.z : d.x, sl, 64);
            ws[k]   = __shfl(__int_as_float((k & 1) ? d.w : d.y), sl, 64);
        }
        int4 d1;
        if (e0 + 8 < e1) d1 = ((const int4*)(edge2 + e0 + 8))[fl];
        uint4 rr[8];
#pragma unroll
        for (int k = 0; k < 8; ++k) rr[k] = X8[(size_t)srcs[k] * 4 + fl];

        for (int e = e0; e < e1; ) {
            int en = e + 8;
            uint4 rn[8]; float wn[8];
            if (en < e1) {
                int sn[8];
#pragma unroll
                for (int k = 0; k < 8; ++k) {
                    int sl = quadbase + (k >> 1);
                    sn[k] = __shfl((k & 1) ? d1.z : d1.x, sl, 64);
                    wn[k] = __shfl(__int_as_float((k & 1) ? d1.w : d1.y), sl, 64);
                }
                if (en + 8 < e1) d1 = ((const int4*)(edge2 + en + 8))[fl];
#pragma unroll
                for (int k = 0; k < 8; ++k) rn[k] = X8[(size_t)sn[k] * 4 + fl];
            }
#pragma unroll
            for (int k = 0; k < 8; ++k) {
                float x[16];
                fp8x16_to_f(rr[k], x);
#pragma unroll
                for (int j = 0; j < 16; ++j)
                    acc[j] = fmaf(ws[k], x[j], acc[j]);
            }
            e = en;
            if (e < e1) {
#pragma unroll
                for (int k = 0; k < 8; ++k) { rr[k] = rn[k]; ws[k] = wn[k]; }
            }
        }
    }
    // teleport: h0 fp16, feats [fl*16, fl*16+16) = float4 slots fl*2, fl*2+1
    f8 ha = h16_to_f8(H04[(size_t)n * 8 + fl * 2]);
    f8 hb = h16_to_f8(H04[(size_t)n * 8 + fl * 2 + 1]);
    float o[16];
#pragma unroll
    for (int j = 0; j < 8; ++j) {
        o[j] = fmaf(0.9f, acc[j], 0.1f * ha.v[j]);
        o[8 + j] = fmaf(0.9f, acc[8 + j], 0.1f * hb.v[j]);
    }
    if (OUT16) {
        f8 lo, hi;
#pragma unroll
        for (int j = 0; j < 8; ++j) { lo.v[j] = o[j]; hi.v[j] = o[8 + j]; }
        Y16[(size_t)n * 8 + fl * 2] = f8_to_h16(lo);
        Y16[(size_t)n * 8 + fl * 2 + 1] = f8_to_h16(hi);
    } else {
        Y8[(size_t)n * 4 + fl] = f_to_fp8x16(o);
    }
}

// ---------------- FC + log_softmax (fp16 in, fp32 out) ----------------
__global__ __launch_bounds__(256) void final_k(const float2* __restrict__ H2,
                                               const float* __restrict__ Wfc,
                                               const float* __restrict__ bfc,
                                               float* __restrict__ out) {
    const int t = threadIdx.x;
    const int n0 = blockIdx.x * 64;
    const int r0 = (t >> 4) << 2;
    const int c0 = (t & 15) << 2;

    int r[4];
#pragma unroll
    for (int j = 0; j < 4; ++j) {
        int rr = n0 + r0 + j;
        r[j] = rr < NN ? rr : NN - 1;
    }
    const float2* Xr[4];
#pragma unroll
    for (int j = 0; j < 4; ++j) Xr[j] = H2 + (size_t)r[j] * 16;

    float4 bf = *(const float4*)(bfc + c0);
    float acc[4][4];
#pragma unroll
    for (int j = 0; j < 4; ++j) {
        acc[j][0] = bf.x; acc[j][1] = bf.y; acc[j][2] = bf.z; acc[j][3] = bf.w;
    }

#pragma unroll 4
    for (int kq = 0; kq < 16; ++kq) {
        float4 xv[4];
#pragma unroll
        for (int j = 0; j < 4; ++j) xv[j] = h8_to_f4(Xr[j][kq]);
        float4 wv[4];
#pragma unroll
        for (int i = 0; i < 4; ++i)
            wv[i] = *(const float4*)(Wfc + (size_t)(kq * 4 + i) * 64 + c0);
#pragma unroll
        for (int j = 0; j < 4; ++j) {
            acc[j][0] = fmaf(xv[j].x, wv[0].x, acc[j][0]);
            acc[j][1] = fmaf(xv[j].x, wv[0].y, acc[j][1]);
            acc[j][2] = fmaf(xv[j].x, wv[0].z, acc[j][2]);
            acc[j][3] = fmaf(xv[j].x, wv[0].w, acc[j][3]);
            acc[j][0] = fmaf(xv[j].y, wv[1].x, acc[j][0]);
            acc[j][1] = fmaf(xv[j].y, wv[1].y, acc[j][1]);
            acc[j][2] = fmaf(xv[j].y, wv[1].z, acc[j][2]);
            acc[j][3] = fmaf(xv[j].y, wv[1].w, acc[j][3]);
            acc[j][0] = fmaf(xv[j].z, wv[2].x, acc[j][0]);
            acc[j][1] = fmaf(xv[j].z, wv[2].y, acc[j][1]);
            acc[j][2] = fmaf(xv[j].z, wv[2].z, acc[j][2]);
            acc[j][3] = fmaf(xv[j].z, wv[2].w, acc[j][3]);
            acc[j][0] = fmaf(xv[j].w, wv[3].x, acc[j][0]);
            acc[j][1] = fmaf(xv[j].w, wv[3].y, acc[j][1]);
            acc[j][2] = fmaf(xv[j].w, wv[3].z, acc[j][2]);
            acc[j][3] = fmaf(xv[j].w, wv[3].w, acc[j][3]);
        }
    }

#pragma unroll
    for (int j = 0; j < 4; ++j) {
        float m = fmaxf(fmaxf(acc[j][0], acc[j][1]), fmaxf(acc[j][2], acc[j][3]));
#pragma unroll
        for (int d = 1; d <= 8; d <<= 1) m = fmaxf(m, __shfl_xor(m, d, 64));
        float s = expf(acc[j][0] - m) + expf(acc[j][1] - m) +
                  expf(acc[j][2] - m) + expf(acc[j][3] - m);
#pragma unroll
        for (int d = 1; d <= 8; d <<= 1) s += __shfl_xor(s, d, 64);
        float lse = m + logf(s);
        int rr = n0 + r0 + j;
        if (rr < NN)
            *(float4*)(out + (size_t)rr * 64 + c0) =
                make_float4(acc[j][0] - lse, acc[j][1] - lse,
                            acc[j][2] - lse, acc[j][3] - lse);
    }
}

// ---------------- host launch ----------------

static inline char* alignup(char* p, size_t a) {
    return (char*)(((uintptr_t)p + a - 1) & ~(uintptr_t)(a - 1));
}

extern "C" void kernel_launch(void* const* d_in, const int* in_sizes, int n_in,
                              void* d_out, int out_size, void* d_ws, size_t ws_size,
                              hipStream_t stream) {
    const float* x   = (const float*)d_in[0];
    const int*   ei  = (const int*)d_in[1];
    const float* W1  = (const float*)d_in[2];
    const float* b1  = (const float*)d_in[3];
    const float* W2  = (const float*)d_in[4];
    const float* b2  = (const float*)d_in[5];
    const float* Wx  = (const float*)d_in[6];
    const float* bx  = (const float*)d_in[7];
    const float* g1  = (const float*)d_in[8];
    const float* be1 = (const float*)d_in[9];
    const float* g2  = (const float*)d_in[10];
    const float* be2 = (const float*)d_in[11];
    const float* g3  = (const float*)d_in[12];
    const float* be3 = (const float*)d_in[13];
    const float* Wfc = (const float*)d_in[14];
    const float* bfc = (const float*)d_in[15];
    float* out = (float*)d_out;

    const int* srcA = ei;
    const int* dstA = ei + NE;

    char* p = (char*)d_ws;
    int*   deg    = (int*)p;   p += NN * 4;
    int*   cursor = (int*)p;   p += NN * 4;
    float* stats  = (float*)p; p += 512 * 4;
    size_t zbytes = (size_t)(p - (char*)d_ws);
    p = alignup(p, 512);
    int*   offs  = (int*)p;    p += (NN + 4) * 4;   p = alignup(p, 512);
    float* dinv  = (float*)p;  p += NN * 4;         p = alignup(p, 512);
    int*   bsum  = (int*)p;    p += 256 * 4;
    int*   bpre  = (int*)p;    p += 256 * 4;        p = alignup(p, 512);
    int2*  edge2 = (int2*)p;   p += ((size_t)NE + 8 * NN + 256) * 8; p = alignup(p, 512);
    float4* tmpH = (float4*)p; p += (size_t)NN * 64 * 2; p = alignup(p, 512);
    float4* hbH  = (float4*)p; p += (size_t)NN * 64 * 2; p = alignup(p, 512);
    float4* apH  = (float4*)p; p += (size_t)NN * 64 * 2; p = alignup(p, 512);
    float4* pbH  = (float4*)p; p += (size_t)NN * 64 * 2; p = alignup(p, 512);
    uint4*  x8a  = (uint4*)p;  p += (size_t)NN * 64;     p = alignup(p, 512);
    uint4*  x8b  = (uint4*)p;  p += (size_t)NN * 64;

    hipMemsetAsync(d_ws, 0, zbytes, stream);

    count_k<<<(NE + 255) / 256, 256, 0, stream>>>(dstA, deg);
    dinv_k<<<(NN + 255) / 256, 256, 0, stream>>>(deg, dinv);
    scan1_k<<<SCAN_B, 256, 0, stream>>>(deg, offs, bsum);
    scan2_k<<<1, 256, 0, stream>>>(bsum, bpre, offs);
    scan3_k<<<(NN + 255) / 256, 256, 0, stream>>>(offs, bpre);
    pad_k<<<(NN + 255) / 256, 256, 0, stream>>>(deg, offs, edge2);
    scatter_k<<<(NE + 255) / 256, 256, 0, stream>>>(srcA, dstA, offs, cursor, dinv, edge2);

    const int MMG = (NN + 63) / 64;          // 782
    const int PG  = (NGRP + 3) / 4;          // 1563: one octet per wave
    const int AG  = (NG16 + 3) / 4;          // 782:  one 16-group per wave
    const int BNG = (NN * 8 + 255) / 256;    // 1563

    mm_k<INF_, false><<<MMG, 256, 0, stream>>>(x, W1, (float2*)tmpH);
    prop_stats_k<<<PG, 256, 0, stream>>>(tmpH, offs, edge2, dinv, b1, pbH, stats + 0 * 128);
    bn_relu_k<<<BNG, 256, 0, stream>>>(pbH, stats + 0 * 128, g1, be1, hbH);

    mm_k<HID, true><<<MMG, 256, 0, stream>>>(hbH, W2, (float2*)tmpH);
    prop_stats_k<<<PG, 256, 0, stream>>>(tmpH, offs, edge2, dinv, b2, pbH, stats + 1 * 128);
    bn_relu_k<<<BNG, 256, 0, stream>>>(pbH, stats + 1 * 128, g2, be2, hbH);

    for (int L = 0; L < 2; ++L) {
        mm_k<HID, true><<<MMG, 256, 0, stream>>>(hbH, Wx + (size_t)L * 64 * 64, (float2*)tmpH);
        prop_stats_k<<<PG, 256, 0, stream>>>(tmpH, offs, edge2, dinv, bx + (size_t)L * 64,
                                             pbH, stats + (2 + L) * 128);
        bn_relu_k<<<BNG, 256, 0, stream>>>(pbH, stats + (2 + L) * 128, g3, be3, hbH);
    }

    // APPNP in fp8: x8a <- fp8(hbH); 9 fp8->fp8 iters ping-pong; 10th -> fp16 apH
    cvt16to8_k<<<BNG, 256, 0, stream>>>(hbH, (uint2*)x8a);
    const uint4* cur8 = x8a;
    for (int it = 0; it < 9; ++it) {
        uint4* o8 = (cur8 == x8a) ? x8b : x8a;
        appnp8_k<false><<<AG, 256, 0, stream>>>(cur8, hbH, offs, edge2, dinv, o8, nullptr);
        cur8 = o8;
    }
    appnp8_k<true><<<AG, 256, 0, stream>>>(cur8, hbH, offs, edge2, dinv, nullptr, apH);

    final_k<<<MMG, 256, 0, stream>>>((const float2*)apH, Wfc, bfc, out);
}

// Round 11
// 528.770 us; speedup vs baseline: 1.2102x; 1.2102x over previous
//
#include <hip/hip_runtime.h>
#include <hip/hip_fp16.h>
#include <cstdint>
#include <cstddef>

#define NN 50000
#define NE 800000
#define HID 64
#define INF_ 128
#define BN_EPS 1e-5f
#define NGRP (NN / 8)        // 6250 node-octets for fp16 props
#define NG16 (NN / 16)       // 3125 node-16-groups for fp8 APPNP
#define SCAN_B 196           // ceil(50000/256)
#define NSLICE 32            // stats partial slices (contention fix)

typedef float floatx2 __attribute__((ext_vector_type(2)));

// ---------------- fp16 pack/unpack ----------------
__device__ __forceinline__ float4 h8_to_f4(float2 raw) {
    union { float f; __half2 h; } ua, ub;
    ua.f = raw.x; ub.f = raw.y;
    float2 fa = __half22float2(ua.h), fb = __half22float2(ub.h);
    return make_float4(fa.x, fa.y, fb.x, fb.y);
}
__device__ __forceinline__ float2 f4_to_h8(float4 v) {
    union { float f; __half2 h; } ua, ub;
    ua.h = __float22half2_rn(make_float2(v.x, v.y));
    ub.h = __float22half2_rn(make_float2(v.z, v.w));
    return make_float2(ua.f, ub.f);
}
struct f8 { float v[8]; };
__device__ __forceinline__ f8 h16_to_f8(float4 raw) {
    f8 r;
    union { float f; __half2 h; } u;
    float2 a;
    u.f = raw.x; a = __half22float2(u.h); r.v[0] = a.x; r.v[1] = a.y;
    u.f = raw.y; a = __half22float2(u.h); r.v[2] = a.x; r.v[3] = a.y;
    u.f = raw.z; a = __half22float2(u.h); r.v[4] = a.x; r.v[5] = a.y;
    u.f = raw.w; a = __half22float2(u.h); r.v[6] = a.x; r.v[7] = a.y;
    return r;
}
__device__ __forceinline__ float4 f8_to_h16(const f8& s) {
    union { float f; __half2 h; } u;
    float4 o;
    u.h = __float22half2_rn(make_float2(s.v[0], s.v[1])); o.x = u.f;
    u.h = __float22half2_rn(make_float2(s.v[2], s.v[3])); o.y = u.f;
    u.h = __float22half2_rn(make_float2(s.v[4], s.v[5])); o.z = u.f;
    u.h = __float22half2_rn(make_float2(s.v[6], s.v[7])); o.w = u.f;
    return o;
}

// ---------------- fp8 e4m3 (OCP, gfx950 HW cvt) pack/unpack ----------------
__device__ __forceinline__ void fp8x8_to_f(unsigned lo, unsigned hi, float out[8]) {
    floatx2 a = __builtin_amdgcn_cvt_pk_f32_fp8((int)lo, false);
    floatx2 b = __builtin_amdgcn_cvt_pk_f32_fp8((int)lo, true);
    floatx2 c = __builtin_amdgcn_cvt_pk_f32_fp8((int)hi, false);
    floatx2 d = __builtin_amdgcn_cvt_pk_f32_fp8((int)hi, true);
    out[0] = a[0]; out[1] = a[1]; out[2] = b[0]; out[3] = b[1];
    out[4] = c[0]; out[5] = c[1]; out[6] = d[0]; out[7] = d[1];
}
__device__ __forceinline__ void fp8x16_to_f(uint4 r, float out[16]) {
    fp8x8_to_f(r.x, r.y, out);
    fp8x8_to_f(r.z, r.w, out + 8);
}
__device__ __forceinline__ uint2 f_to_fp8x8(const float v[8]) {
    int w0 = __builtin_amdgcn_cvt_pk_fp8_f32(v[0], v[1], 0, false);
    w0 = __builtin_amdgcn_cvt_pk_fp8_f32(v[2], v[3], w0, true);
    int w1 = __builtin_amdgcn_cvt_pk_fp8_f32(v[4], v[5], 0, false);
    w1 = __builtin_amdgcn_cvt_pk_fp8_f32(v[6], v[7], w1, true);
    uint2 o; o.x = (unsigned)w0; o.y = (unsigned)w1;
    return o;
}
__device__ __forceinline__ uint4 f_to_fp8x16(const float v[16]) {
    uint2 a = f_to_fp8x8(v), b = f_to_fp8x8(v + 8);
    uint4 o; o.x = a.x; o.y = a.y; o.z = b.x; o.w = b.y;
    return o;
}

// ---------------- graph prep ----------------

__global__ void count_k(const int* __restrict__ dst, int* __restrict__ cnt) {
    int e = blockIdx.x * blockDim.x + threadIdx.x;
    if (e < NE) atomicAdd(&cnt[dst[e]], 1);
}

__global__ void dinv_k(const int* __restrict__ cnt, float* __restrict__ dinv) {
    int n = blockIdx.x * blockDim.x + threadIdx.x;
    if (n < NN) dinv[n] = rsqrtf((float)(cnt[n] + 1));   // +1 self-loop
}

// parallel scan of PADDED degrees ((deg+7)&~7) -> offs; 3 kernels
__global__ void scan1_k(const int* __restrict__ cnt, int* __restrict__ offs,
                        int* __restrict__ bsum) {
    __shared__ int sh[256];
    int t = threadIdx.x, i = blockIdx.x * 256 + t;
    int v = (i < NN) ? ((cnt[i] + 7) & ~7) : 0;
    sh[t] = v;
    __syncthreads();
    for (int d = 1; d < 256; d <<= 1) {
        int u = (t >= d) ? sh[t - d] : 0;
        __syncthreads();
        sh[t] += u;
        __syncthreads();
    }
    if (i < NN) offs[i] = sh[t] - v;
    if (t == 255) bsum[blockIdx.x] = sh[255];
}

__global__ void scan2_k(const int* __restrict__ bsum, int* __restrict__ bpre,
                        int* __restrict__ offs) {
    __shared__ int sh[256];
    int t = threadIdx.x;
    int v = (t < SCAN_B) ? bsum[t] : 0;
    sh[t] = v;
    __syncthreads();
    for (int d = 1; d < 256; d <<= 1) {
        int u = (t >= d) ? sh[t - d] : 0;
        __syncthreads();
        sh[t] += u;
        __syncthreads();
    }
    bpre[t] = sh[t] - v;
    if (t == 255) offs[NN] = sh[255];
}

__global__ void scan3_k(int* __restrict__ offs, const int* __restrict__ bpre) {
    int i = blockIdx.x * blockDim.x + threadIdx.x;
    if (i < NN) offs[i] += bpre[i >> 8];
}

__global__ void pad_k(const int* __restrict__ cnt, const int* __restrict__ offs,
                      int2* __restrict__ edge2) {
    int n = blockIdx.x * blockDim.x + threadIdx.x;
    if (n >= NN) return;
    int e = offs[n] + cnt[n], e1 = offs[n + 1];
    for (; e < e1; ++e) edge2[e] = make_int2(0, 0);   // w = 0.0f -> row 0, hot line
}

__global__ void scatter_k(const int* __restrict__ src, const int* __restrict__ dst,
                          const int* __restrict__ offs, int* __restrict__ cursor,
                          const float* __restrict__ dinv,
                          int2* __restrict__ edge2) {
    int e = blockIdx.x * blockDim.x + threadIdx.x;
    if (e < NE) {
        int s = src[e], d = dst[e];
        int pos = offs[d] + atomicAdd(&cursor[d], 1);
        edge2[pos] = make_int2(s, __float_as_int(dinv[s] * dinv[d]));
    }
}

// ---------------- dense matmul: Y[N,64] = X[N,K] @ W[K,64], fp16 out --------
template <int K, bool HIN>
__global__ __launch_bounds__(256) void mm_k(const void* __restrict__ Xv,
                                            const float* __restrict__ W,
                                            float2* __restrict__ Y) {
    const int t = threadIdx.x;
    const int n0 = blockIdx.x * 64;
    const int r0 = (t >> 4) << 2;
    const int c0 = (t & 15) << 2;

    int r[4];
#pragma unroll
    for (int j = 0; j < 4; ++j) {
        int rr = n0 + r0 + j;
        r[j] = rr < NN ? rr : NN - 1;
    }
    const float4* Xr4[4];
    const float2* Xr2[4];
#pragma unroll
    for (int j = 0; j < 4; ++j) {
        if (HIN) Xr2[j] = (const float2*)Xv + (size_t)r[j] * (K / 4);
        else     Xr4[j] = (const float4*)Xv + (size_t)r[j] * (K / 4);
    }

    float acc[4][4];
#pragma unroll
    for (int j = 0; j < 4; ++j)
#pragma unroll
        for (int c = 0; c < 4; ++c) acc[j][c] = 0.f;

#pragma unroll 4
    for (int kq = 0; kq < K / 4; ++kq) {
        float4 xv[4];
#pragma unroll
        for (int j = 0; j < 4; ++j)
            xv[j] = HIN ? h8_to_f4(Xr2[j][kq]) : Xr4[j][kq];
        float4 wv[4];
#pragma unroll
        for (int i = 0; i < 4; ++i)
            wv[i] = *(const float4*)(W + (size_t)(kq * 4 + i) * 64 + c0);
#pragma unroll
        for (int j = 0; j < 4; ++j) {
            acc[j][0] = fmaf(xv[j].x, wv[0].x, acc[j][0]);
            acc[j][1] = fmaf(xv[j].x, wv[0].y, acc[j][1]);
            acc[j][2] = fmaf(xv[j].x, wv[0].z, acc[j][2]);
            acc[j][3] = fmaf(xv[j].x, wv[0].w, acc[j][3]);
            acc[j][0] = fmaf(xv[j].y, wv[1].x, acc[j][0]);
            acc[j][1] = fmaf(xv[j].y, wv[1].y, acc[j][1]);
            acc[j][2] = fmaf(xv[j].y, wv[1].z, acc[j][2]);
            acc[j][3] = fmaf(xv[j].y, wv[1].w, acc[j][3]);
            acc[j][0] = fmaf(xv[j].z, wv[2].x, acc[j][0]);
            acc[j][1] = fmaf(xv[j].z, wv[2].y, acc[j][1]);
            acc[j][2] = fmaf(xv[j].z, wv[2].z, acc[j][2]);
            acc[j][3] = fmaf(xv[j].z, wv[2].w, acc[j][3]);
            acc[j][0] = fmaf(xv[j].w, wv[3].x, acc[j][0]);
            acc[j][1] = fmaf(xv[j].w, wv[3].y, acc[j][1]);
            acc[j][2] = fmaf(xv[j].w, wv[3].z, acc[j][2]);
            acc[j][3] = fmaf(xv[j].w, wv[3].w, acc[j][3]);
        }
    }

#pragma unroll
    for (int j = 0; j < 4; ++j) {
        int rr = n0 + r0 + j;
        if (rr < NN)
            Y[(size_t)rr * 16 + (t & 15)] =
                f4_to_h8(make_float4(acc[j][0], acc[j][1], acc[j][2], acc[j][3]));
    }
}

// ---- fp16 propagate core: software-pipelined, sched_barrier-pinned --------
// lane = slot*8 + fl; slot in [0,8), fl in [0,8). slotbase = lane & 56.
__device__ __forceinline__ void prop_gather8(const float4* __restrict__ X4,
                                             const int2* __restrict__ E,
                                             int e0, int e1, int fl, int slotbase,
                                             float acc[8], float acc2[8]) {
    if (e0 >= e1) return;
    int2 d0 = E[e0 + fl];
    int srcs[8]; float ws[8];
#pragma unroll
    for (int i = 0; i < 8; ++i) {
        srcs[i] = __shfl(d0.x, slotbase + i, 64);
        ws[i]   = __shfl(__int_as_float(d0.y), slotbase + i, 64);
    }
    int2 d1;
    if (e0 + 8 < e1) d1 = E[e0 + 8 + fl];
    float4 rr[8];
#pragma unroll
    for (int i = 0; i < 8; ++i) rr[i] = X4[(size_t)srcs[i] * 8 + fl];

    for (int e = e0; e < e1; ) {
        int en = e + 8;
        float4 rn[8]; float wn[8];
        if (en < e1) {
            int sn[8];
#pragma unroll
            for (int i = 0; i < 8; ++i) {
                sn[i] = __shfl(d1.x, slotbase + i, 64);
                wn[i] = __shfl(__int_as_float(d1.y), slotbase + i, 64);
            }
            if (en + 8 < e1) d1 = E[en + 8 + fl];
#pragma unroll
            for (int i = 0; i < 8; ++i) rn[i] = X4[(size_t)sn[i] * 8 + fl];
        }
        // pin: next batch's gathers must be ISSUED before this consume
        __builtin_amdgcn_sched_barrier(0);
#pragma unroll
        for (int i = 0; i < 8; ++i) {
            f8 x = h16_to_f8(rr[i]);
            float* a = (i & 1) ? acc2 : acc;
#pragma unroll
            for (int j = 0; j < 8; ++j)
                a[j] = fmaf(ws[i], x.v[j], a[j]);
        }
        e = en;
        if (e < e1) {
#pragma unroll
            for (int i = 0; i < 8; ++i) { rr[i] = rn[i]; ws[i] = wn[i]; }
        }
    }
}

// ---------------- propagate + bias + BN-stats (fp16 in, fp16 out) ----------
// stats: 32 partial slices x 128 floats (block -> slice blockIdx&31) to kill
// the 1563-way same-address atomic serialization seen through R10.
__global__ __launch_bounds__(256, 2) void prop_stats_k(
        const float4* __restrict__ X4, const int* __restrict__ offs,
        const int2* __restrict__ edge2, const float* __restrict__ dinv,
        const float* __restrict__ bias, float4* __restrict__ Y4,
        float* __restrict__ stats) {
    const int lane = threadIdx.x & 63;
    const int wave = threadIdx.x >> 6;
    const int slot = lane >> 3;
    const int fl = lane & 7;
    const int slotbase = lane & 56;
    const int wid = blockIdx.x * 4 + wave;
    const int nw = gridDim.x * 4;

    float bias8[8];
    {
        float4 b0 = ((const float4*)bias)[fl * 2];
        float4 b1 = ((const float4*)bias)[fl * 2 + 1];
        bias8[0] = b0.x; bias8[1] = b0.y; bias8[2] = b0.z; bias8[3] = b0.w;
        bias8[4] = b1.x; bias8[5] = b1.y; bias8[6] = b1.z; bias8[7] = b1.w;
    }

    float s1[8], s2[8];
#pragma unroll
    for (int j = 0; j < 8; ++j) { s1[j] = 0.f; s2[j] = 0.f; }

    for (int g = wid; g < NGRP; g += nw) {
        int n = g * 8 + slot;
        float dn = dinv[n];
        float dd = dn * dn;
        f8 self = h16_to_f8(X4[(size_t)n * 8 + fl]);
        float acc[8], acc2[8];
#pragma unroll
        for (int j = 0; j < 8; ++j) { acc[j] = dd * self.v[j]; acc2[j] = 0.f; }
        int e0 = offs[n], e1 = offs[n + 1];
        prop_gather8(X4, edge2, e0, e1, fl, slotbase, acc, acc2);
        f8 o;
#pragma unroll
        for (int j = 0; j < 8; ++j) {
            float a = acc[j] + acc2[j] + bias8[j];
            o.v[j] = a;
            s1[j] += a;
            s2[j] = fmaf(a, a, s2[j]);
        }
        Y4[(size_t)n * 8 + fl] = f8_to_h16(o);
    }

    // reduce across the 8 slots (lanes differing in bits 3,4,5)
#pragma unroll
    for (int m = 8; m <= 32; m <<= 1) {
#pragma unroll
        for (int j = 0; j < 8; ++j) {
            s1[j] += __shfl_xor(s1[j], m, 64);
            s2[j] += __shfl_xor(s2[j], m, 64);
        }
    }

    __shared__ float red[4][8][16];
    if (lane < 8) {
#pragma unroll
        for (int j = 0; j < 8; ++j) {
            red[wave][lane][j] = s1[j];
            red[wave][lane][8 + j] = s2[j];
        }
    }
    __syncthreads();
    int t = threadIdx.x;
    if (t < 128) {
        int j = t & 63;            // feature index
        int isq = t >> 6;          // 0 = sum, 1 = sumsq
        int fli = j >> 3, c = (j & 7) + isq * 8;
        float a = red[0][fli][c] + red[1][fli][c] + red[2][fli][c] + red[3][fli][c];
        atomicAdd(&stats[(blockIdx.x & (NSLICE - 1)) * 128 + isq * 64 + j], a);
    }
}

// ------- batchnorm + relu: fp16 in -> fp16 out; reduces 32 stat slices -----
__global__ __launch_bounds__(256) void bn_relu_k(
        const float4* __restrict__ Y4, const float* __restrict__ slices,
        const float* __restrict__ g, const float* __restrict__ be,
        float4* __restrict__ H4) {
    __shared__ float fs[128];
    int t = threadIdx.x;
    if (t < 128) {
        float s = 0.f;
#pragma unroll
        for (int k = 0; k < NSLICE; ++k) s += slices[k * 128 + t];
        fs[t] = s;
    }
    __syncthreads();
    int i = blockIdx.x * blockDim.x + t;
    if (i >= NN * 8) return;
    int fg = i & 7;                 // feats [fg*8, fg*8+8)
    const float invN = 1.f / (float)NN;
    f8 y = h16_to_f8(Y4[i]);
    float4 gv0 = ((const float4*)g)[fg * 2];
    float4 gv1 = ((const float4*)g)[fg * 2 + 1];
    float4 bv0 = ((const float4*)be)[fg * 2];
    float4 bv1 = ((const float4*)be)[fg * 2 + 1];
    float gv[8] = { gv0.x, gv0.y, gv0.z, gv0.w, gv1.x, gv1.y, gv1.z, gv1.w };
    float bv[8] = { bv0.x, bv0.y, bv0.z, bv0.w, bv1.x, bv1.y, bv1.z, bv1.w };
    f8 o;
#pragma unroll
    for (int j = 0; j < 8; ++j) {
        float m = fs[fg * 8 + j] * invN;
        float v = fs[64 + fg * 8 + j] * invN - m * m;
        float val = fmaf(gv[j] * rsqrtf(v + BN_EPS), y.v[j] - m, bv[j]);
        o.v[j] = val > 0.f ? val : 0.f;
    }
    H4[i] = f8_to_h16(o);
}

// ---------------- fp16 -> fp8 row conversion ----------------
__global__ void cvt16to8_k(const float4* __restrict__ H4, uint2* __restrict__ X8) {
    int i = blockIdx.x * blockDim.x + threadIdx.x;
    if (i >= NN * 8) return;
    f8 v = h16_to_f8(H4[i]);
    X8[i] = f_to_fp8x8(v.v);
}

// ---- fp8 APPNP: 16 nodes/wave, pipelined + sched_barrier-pinned -----------
// lane = slot*4 + fl; slot in [0,16), fl in [0,4) -> feats [fl*16, fl*16+16)
template <bool OUT16>
__global__ __launch_bounds__(256, 2) void appnp8_k(
        const uint4* __restrict__ X8, const float4* __restrict__ H04,
        const int* __restrict__ offs, const int2* __restrict__ edge2,
        const float* __restrict__ dinv,
        uint4* __restrict__ Y8, float4* __restrict__ Y16) {
    const int lane = threadIdx.x & 63;
    const int wave = threadIdx.x >> 6;
    const int slot = lane >> 2;
    const int fl = lane & 3;
    const int quadbase = lane & 60;
    const int wid = blockIdx.x * 4 + wave;
    if (wid >= NG16) return;
    int n = wid * 16 + slot;
    float dn = dinv[n];
    float dd = dn * dn;
    float acc[16];
    {
        float self[16];
        fp8x16_to_f(X8[(size_t)n * 4 + fl], self);
#pragma unroll
        for (int j = 0; j < 16; ++j) acc[j] = dd * self[j];
    }
    int e0 = offs[n], e1 = offs[n + 1];
    if (e0 < e1) {
        int4 d = ((const int4*)(edge2 + e0))[fl];   // 2 edges per lane
        int srcs[8]; float ws[8];
#pragma unroll
        for (int k = 0; k < 8; ++k) {
            int sl = quadbase + (k >> 1);
            srcs[k] = __shfl((k & 1) ? d.z : d.x, sl, 64);
            ws[k]   = __shfl(__int_as_float((k & 1) ? d.w : d.y), sl, 64);
        }
        int4 d1;
        if (e0 + 8 < e1) d1 = ((const int4*)(edge2 + e0 + 8))[fl];
        uint4 rr[8];
#pragma unroll
        for (int k = 0; k < 8; ++k) rr[k] = X8[(size_t)srcs[k] * 4 + fl];

        for (int e = e0; e < e1; ) {
            int en = e + 8;
            uint4 rn[8]; float wn[8];
            if (en < e1) {
                int sn[8];
#pragma unroll
                for (int k = 0; k < 8; ++k) {
                    int sl = quadbase + (k >> 1);
                    sn[k] = __shfl((k & 1) ? d1.z : d1.x, sl, 64);
                    wn[k] = __shfl(__int_as_float((k & 1) ? d1.w : d1.y), sl, 64);
                }
                if (en + 8 < e1) d1 = ((const int4*)(edge2 + en + 8))[fl];
#pragma unroll
                for (int k = 0; k < 8; ++k) rn[k] = X8[(size_t)sn[k] * 4 + fl];
            }
            __builtin_amdgcn_sched_barrier(0);
#pragma unroll
            for (int k = 0; k < 8; ++k) {
                float x[16];
                fp8x16_to_f(rr[k], x);
#pragma unroll
                for (int j = 0; j < 16; ++j)
                    acc[j] = fmaf(ws[k], x[j], acc[j]);
            }
            e = en;
            if (e < e1) {
#pragma unroll
                for (int k = 0; k < 8; ++k) { rr[k] = rn[k]; ws[k] = wn[k]; }
            }
        }
    }
    // teleport: h0 fp16, feats [fl*16, fl*16+16) = float4 slots fl*2, fl*2+1
    f8 ha = h16_to_f8(H04[(size_t)n * 8 + fl * 2]);
    f8 hb = h16_to_f8(H04[(size_t)n * 8 + fl * 2 + 1]);
    float o[16];
#pragma unroll
    for (int j = 0; j < 8; ++j) {
        o[j] = fmaf(0.9f, acc[j], 0.1f * ha.v[j]);
        o[8 + j] = fmaf(0.9f, acc[8 + j], 0.1f * hb.v[j]);
    }
    if (OUT16) {
        f8 lo, hi;
#pragma unroll
        for (int j = 0; j < 8; ++j) { lo.v[j] = o[j]; hi.v[j] = o[8 + j]; }
        Y16[(size_t)n * 8 + fl * 2] = f8_to_h16(lo);
        Y16[(size_t)n * 8 + fl * 2 + 1] = f8_to_h16(hi);
    } else {
        Y8[(size_t)n * 4 + fl] = f_to_fp8x16(o);
    }
}

// ---------------- FC + log_softmax (fp16 in, fp32 out) ----------------
__global__ __launch_bounds__(256) void final_k(const float2* __restrict__ H2,
                                               const float* __restrict__ Wfc,
                                               const float* __restrict__ bfc,
                                               float* __restrict__ out) {
    const int t = threadIdx.x;
    const int n0 = blockIdx.x * 64;
    const int r0 = (t >> 4) << 2;
    const int c0 = (t & 15) << 2;

    int r[4];
#pragma unroll
    for (int j = 0; j < 4; ++j) {
        int rr = n0 + r0 + j;
        r[j] = rr < NN ? rr : NN - 1;
    }
    const float2* Xr[4];
#pragma unroll
    for (int j = 0; j < 4; ++j) Xr[j] = H2 + (size_t)r[j] * 16;

    float4 bf = *(const float4*)(bfc + c0);
    float acc[4][4];
#pragma unroll
    for (int j = 0; j < 4; ++j) {
        acc[j][0] = bf.x; acc[j][1] = bf.y; acc[j][2] = bf.z; acc[j][3] = bf.w;
    }

#pragma unroll 4
    for (int kq = 0; kq < 16; ++kq) {
        float4 xv[4];
#pragma unroll
        for (int j = 0; j < 4; ++j) xv[j] = h8_to_f4(Xr[j][kq]);
        float4 wv[4];
#pragma unroll
        for (int i = 0; i < 4; ++i)
            wv[i] = *(const float4*)(Wfc + (size_t)(kq * 4 + i) * 64 + c0);
#pragma unroll
        for (int j = 0; j < 4; ++j) {
            acc[j][0] = fmaf(xv[j].x, wv[0].x, acc[j][0]);
            acc[j][1] = fmaf(xv[j].x, wv[0].y, acc[j][1]);
            acc[j][2] = fmaf(xv[j].x, wv[0].z, acc[j][2]);
            acc[j][3] = fmaf(xv[j].x, wv[0].w, acc[j][3]);
            acc[j][0] = fmaf(xv[j].y, wv[1].x, acc[j][0]);
            acc[j][1] = fmaf(xv[j].y, wv[1].y, acc[j][1]);
            acc[j][2] = fmaf(xv[j].y, wv[1].z, acc[j][2]);
            acc[j][3] = fmaf(xv[j].y, wv[1].w, acc[j][3]);
            acc[j][0] = fmaf(xv[j].z, wv[2].x, acc[j][0]);
            acc[j][1] = fmaf(xv[j].z, wv[2].y, acc[j][1]);
            acc[j][2] = fmaf(xv[j].z, wv[2].z, acc[j][2]);
            acc[j][3] = fmaf(xv[j].z, wv[2].w, acc[j][3]);
            acc[j][0] = fmaf(xv[j].w, wv[3].x, acc[j][0]);
            acc[j][1] = fmaf(xv[j].w, wv[3].y, acc[j][1]);
            acc[j][2] = fmaf(xv[j].w, wv[3].z, acc[j][2]);
            acc[j][3] = fmaf(xv[j].w, wv[3].w, acc[j][3]);
        }
    }

#pragma unroll
    for (int j = 0; j < 4; ++j) {
        float m = fmaxf(fmaxf(acc[j][0], acc[j][1]), fmaxf(acc[j][2], acc[j][3]));
#pragma unroll
        for (int d = 1; d <= 8; d <<= 1) m = fmaxf(m, __shfl_xor(m, d, 64));
        float s = expf(acc[j][0] - m) + expf(acc[j][1] - m) +
                  expf(acc[j][2] - m) + expf(acc[j][3] - m);
#pragma unroll
        for (int d = 1; d <= 8; d <<= 1) s += __shfl_xor(s, d, 64);
        float lse = m + logf(s);
        int rr = n0 + r0 + j;
        if (rr < NN)
            *(float4*)(out + (size_t)rr * 64 + c0) =
                make_float4(acc[j][0] - lse, acc[j][1] - lse,
                            acc[j][2] - lse, acc[j][3] - lse);
    }
}

// ---------------- host launch ----------------

static inline char* alignup(char* p, size_t a) {
    return (char*)(((uintptr_t)p + a - 1) & ~(uintptr_t)(a - 1));
}

extern "C" void kernel_launch(void* const* d_in, const int* in_sizes, int n_in,
                              void* d_out, int out_size, void* d_ws, size_t ws_size,
                              hipStream_t stream) {
    const float* x   = (const float*)d_in[0];
    const int*   ei  = (const int*)d_in[1];
    const float* W1  = (const float*)d_in[2];
    const float* b1  = (const float*)d_in[3];
    const float* W2  = (const float*)d_in[4];
    const float* b2  = (const float*)d_in[5];
    const float* Wx  = (const float*)d_in[6];
    const float* bx  = (const float*)d_in[7];
    const float* g1  = (const float*)d_in[8];
    const float* be1 = (const float*)d_in[9];
    const float* g2  = (const float*)d_in[10];
    const float* be2 = (const float*)d_in[11];
    const float* g3  = (const float*)d_in[12];
    const float* be3 = (const float*)d_in[13];
    const float* Wfc = (const float*)d_in[14];
    const float* bfc = (const float*)d_in[15];
    float* out = (float*)d_out;

    const int* srcA = ei;
    const int* dstA = ei + NE;

    char* p = (char*)d_ws;
    int*   deg    = (int*)p;   p += NN * 4;
    int*   cursor = (int*)p;   p += NN * 4;
    float* stats  = (float*)p; p += 4 * NSLICE * 128 * 4;   // 4 layers x 32 slices x 128
    size_t zbytes = (size_t)(p - (char*)d_ws);
    p = alignup(p, 512);
    int*   offs  = (int*)p;    p += (NN + 4) * 4;   p = alignup(p, 512);
    float* dinv  = (float*)p;  p += NN * 4;         p = alignup(p, 512);
    int*   bsum  = (int*)p;    p += 256 * 4;
    int*   bpre  = (int*)p;    p += 256 * 4;        p = alignup(p, 512);
    int2*  edge2 = (int2*)p;   p += ((size_t)NE + 8 * NN + 256) * 8; p = alignup(p, 512);
    float4* tmpH = (float4*)p; p += (size_t)NN * 64 * 2; p = alignup(p, 512);
    float4* hbH  = (float4*)p; p += (size_t)NN * 64 * 2; p = alignup(p, 512);
    float4* apH  = (float4*)p; p += (size_t)NN * 64 * 2; p = alignup(p, 512);
    float4* pbH  = (float4*)p; p += (size_t)NN * 64 * 2; p = alignup(p, 512);
    uint4*  x8a  = (uint4*)p;  p += (size_t)NN * 64;     p = alignup(p, 512);
    uint4*  x8b  = (uint4*)p;  p += (size_t)NN * 64;

    hipMemsetAsync(d_ws, 0, zbytes, stream);

    count_k<<<(NE + 255) / 256, 256, 0, stream>>>(dstA, deg);
    dinv_k<<<(NN + 255) / 256, 256, 0, stream>>>(deg, dinv);
    scan1_k<<<SCAN_B, 256, 0, stream>>>(deg, offs, bsum);
    scan2_k<<<1, 256, 0, stream>>>(bsum, bpre, offs);
    scan3_k<<<(NN + 255) / 256, 256, 0, stream>>>(offs, bpre);
    pad_k<<<(NN + 255) / 256, 256, 0, stream>>>(deg, offs, edge2);
    scatter_k<<<(NE + 255) / 256, 256, 0, stream>>>(srcA, dstA, offs, cursor, dinv, edge2);

    const int MMG = (NN + 63) / 64;          // 782
    const int PG  = (NGRP + 3) / 4;          // 1563: one octet per wave
    const int AG  = (NG16 + 3) / 4;          // 782:  one 16-group per wave
    const int BNG = (NN * 8 + 255) / 256;    // 1563
    const int SL  = NSLICE * 128;            // floats per layer slice block

    mm_k<INF_, false><<<MMG, 256, 0, stream>>>(x, W1, (float2*)tmpH);
    prop_stats_k<<<PG, 256, 0, stream>>>(tmpH, offs, edge2, dinv, b1, pbH, stats + 0 * SL);
    bn_relu_k<<<BNG, 256, 0, stream>>>(pbH, stats + 0 * SL, g1, be1, hbH);

    mm_k<HID, true><<<MMG, 256, 0, stream>>>(hbH, W2, (float2*)tmpH);
    prop_stats_k<<<PG, 256, 0, stream>>>(tmpH, offs, edge2, dinv, b2, pbH, stats + 1 * SL);
    bn_relu_k<<<BNG, 256, 0, stream>>>(pbH, stats + 1 * SL, g2, be2, hbH);

    for (int L = 0; L < 2; ++L) {
        mm_k<HID, true><<<MMG, 256, 0, stream>>>(hbH, Wx + (size_t)L * 64 * 64, (float2*)tmpH);
        prop_stats_k<<<PG, 256, 0, stream>>>(tmpH, offs, edge2, dinv, bx + (size_t)L * 64,
                                             pbH, stats + (2 + L) * SL);
        bn_relu_k<<<BNG, 256, 0, stream>>>(pbH, stats + (2 + L) * SL, g3, be3, hbH);
    }

    // APPNP in fp8: x8a <- fp8(hbH); 9 fp8->fp8 iters ping-pong; 10th -> fp16 apH
    cvt16to8_k<<<BNG, 256, 0, stream>>>(hbH, (uint2*)x8a);
    const uint4* cur8 = x8a;
    for (int it = 0; it < 9; ++it) {
        uint4* o8 = (cur8 == x8a) ? x8b : x8a;
        appnp8_k<false><<<AG, 256, 0, stream>>>(cur8, hbH, offs, edge2, dinv, o8, nullptr);
        cur8 = o8;
    }
    appnp8_k<true><<<AG, 256, 0, stream>>>(cur8, hbH, offs, edge2, dinv, nullptr, apH);

    final_k<<<MMG, 256, 0, stream>>>((const float2*)apH, Wfc, bfc, out);
}

// Round 12
// 504.696 us; speedup vs baseline: 1.2679x; 1.0477x over previous
//
#include <hip/hip_runtime.h>
#include <hip/hip_fp16.h>
#include <cstdint>
#include <cstddef>

#define NN 50000
#define NE 800000
#define HID 64
#define INF_ 128
#define BN_EPS 1e-5f
#define NGRP (NN / 8)        // 6250 node-octets for fp16 props
#define NG16 (NN / 16)       // 3125 node-16-groups for fp8 APPNP
#define SCAN_B 196           // ceil(50000/256)
#define NSLICE 32            // stats partial slices (contention fix)

typedef float floatx2 __attribute__((ext_vector_type(2)));

// ---------------- fp16 pack/unpack ----------------
__device__ __forceinline__ float4 h8_to_f4(float2 raw) {
    union { float f; __half2 h; } ua, ub;
    ua.f = raw.x; ub.f = raw.y;
    float2 fa = __half22float2(ua.h), fb = __half22float2(ub.h);
    return make_float4(fa.x, fa.y, fb.x, fb.y);
}
__device__ __forceinline__ float2 f4_to_h8(float4 v) {
    union { float f; __half2 h; } ua, ub;
    ua.h = __float22half2_rn(make_float2(v.x, v.y));
    ub.h = __float22half2_rn(make_float2(v.z, v.w));
    return make_float2(ua.f, ub.f);
}
struct f8 { float v[8]; };
__device__ __forceinline__ f8 h16_to_f8(float4 raw) {
    f8 r;
    union { float f; __half2 h; } u;
    float2 a;
    u.f = raw.x; a = __half22float2(u.h); r.v[0] = a.x; r.v[1] = a.y;
    u.f = raw.y; a = __half22float2(u.h); r.v[2] = a.x; r.v[3] = a.y;
    u.f = raw.z; a = __half22float2(u.h); r.v[4] = a.x; r.v[5] = a.y;
    u.f = raw.w; a = __half22float2(u.h); r.v[6] = a.x; r.v[7] = a.y;
    return r;
}
__device__ __forceinline__ float4 f8_to_h16(const f8& s) {
    union { float f; __half2 h; } u;
    float4 o;
    u.h = __float22half2_rn(make_float2(s.v[0], s.v[1])); o.x = u.f;
    u.h = __float22half2_rn(make_float2(s.v[2], s.v[3])); o.y = u.f;
    u.h = __float22half2_rn(make_float2(s.v[4], s.v[5])); o.z = u.f;
    u.h = __float22half2_rn(make_float2(s.v[6], s.v[7])); o.w = u.f;
    return o;
}

// ---------------- fp8 e4m3 (OCP, gfx950 HW cvt) pack/unpack ----------------
__device__ __forceinline__ void fp8x8_to_f(unsigned lo, unsigned hi, float out[8]) {
    floatx2 a = __builtin_amdgcn_cvt_pk_f32_fp8((int)lo, false);
    floatx2 b = __builtin_amdgcn_cvt_pk_f32_fp8((int)lo, true);
    floatx2 c = __builtin_amdgcn_cvt_pk_f32_fp8((int)hi, false);
    floatx2 d = __builtin_amdgcn_cvt_pk_f32_fp8((int)hi, true);
    out[0] = a[0]; out[1] = a[1]; out[2] = b[0]; out[3] = b[1];
    out[4] = c[0]; out[5] = c[1]; out[6] = d[0]; out[7] = d[1];
}
__device__ __forceinline__ void fp8x16_to_f(uint4 r, float out[16]) {
    fp8x8_to_f(r.x, r.y, out);
    fp8x8_to_f(r.z, r.w, out + 8);
}
__device__ __forceinline__ uint2 f_to_fp8x8(const float v[8]) {
    int w0 = __builtin_amdgcn_cvt_pk_fp8_f32(v[0], v[1], 0, false);
    w0 = __builtin_amdgcn_cvt_pk_fp8_f32(v[2], v[3], w0, true);
    int w1 = __builtin_amdgcn_cvt_pk_fp8_f32(v[4], v[5], 0, false);
    w1 = __builtin_amdgcn_cvt_pk_fp8_f32(v[6], v[7], w1, true);
    uint2 o; o.x = (unsigned)w0; o.y = (unsigned)w1;
    return o;
}
__device__ __forceinline__ uint4 f_to_fp8x16(const float v[16]) {
    uint2 a = f_to_fp8x8(v), b = f_to_fp8x8(v + 8);
    uint4 o; o.x = a.x; o.y = a.y; o.z = b.x; o.w = b.y;
    return o;
}

// ---------------- graph prep ----------------

__global__ void count_k(const int* __restrict__ dst, int* __restrict__ cnt) {
    int e = blockIdx.x * blockDim.x + threadIdx.x;
    if (e < NE) atomicAdd(&cnt[dst[e]], 1);
}

__global__ void dinv_k(const int* __restrict__ cnt, float* __restrict__ dinv) {
    int n = blockIdx.x * blockDim.x + threadIdx.x;
    if (n < NN) dinv[n] = rsqrtf((float)(cnt[n] + 1));   // +1 self-loop
}

// parallel scan of PADDED degrees ((deg+7)&~7) -> offs; 3 kernels
__global__ void scan1_k(const int* __restrict__ cnt, int* __restrict__ offs,
                        int* __restrict__ bsum) {
    __shared__ int sh[256];
    int t = threadIdx.x, i = blockIdx.x * 256 + t;
    int v = (i < NN) ? ((cnt[i] + 7) & ~7) : 0;
    sh[t] = v;
    __syncthreads();
    for (int d = 1; d < 256; d <<= 1) {
        int u = (t >= d) ? sh[t - d] : 0;
        __syncthreads();
        sh[t] += u;
        __syncthreads();
    }
    if (i < NN) offs[i] = sh[t] - v;
    if (t == 255) bsum[blockIdx.x] = sh[255];
}

__global__ void scan2_k(const int* __restrict__ bsum, int* __restrict__ bpre,
                        int* __restrict__ offs) {
    __shared__ int sh[256];
    int t = threadIdx.x;
    int v = (t < SCAN_B) ? bsum[t] : 0;
    sh[t] = v;
    __syncthreads();
    for (int d = 1; d < 256; d <<= 1) {
        int u = (t >= d) ? sh[t - d] : 0;
        __syncthreads();
        sh[t] += u;
        __syncthreads();
    }
    bpre[t] = sh[t] - v;
    if (t == 255) offs[NN] = sh[255];
}

__global__ void scan3_k(int* __restrict__ offs, const int* __restrict__ bpre) {
    int i = blockIdx.x * blockDim.x + threadIdx.x;
    if (i < NN) offs[i] += bpre[i >> 8];
}

__global__ void pad_k(const int* __restrict__ cnt, const int* __restrict__ offs,
                      int2* __restrict__ edge2) {
    int n = blockIdx.x * blockDim.x + threadIdx.x;
    if (n >= NN) return;
    int e = offs[n] + cnt[n], e1 = offs[n + 1];
    for (; e < e1; ++e) edge2[e] = make_int2(0, 0);   // w = 0.0f -> row 0, hot line
}

__global__ void scatter_k(const int* __restrict__ src, const int* __restrict__ dst,
                          const int* __restrict__ offs, int* __restrict__ cursor,
                          const float* __restrict__ dinv,
                          int2* __restrict__ edge2) {
    int e = blockIdx.x * blockDim.x + threadIdx.x;
    if (e < NE) {
        int s = src[e], d = dst[e];
        int pos = offs[d] + atomicAdd(&cursor[d], 1);
        edge2[pos] = make_int2(s, __float_as_int(dinv[s] * dinv[d]));
    }
}

// ---------------- dense matmul: Y[N,64] = X[N,K] @ W[K,64], fp16 out --------
// LDS-staged: X-tile (64 x K, padded +4) and W both in LDS; staging is a
// coalesced cooperative copy (latency-immune), inner loop is LDS-only ->
// VALU-bound. Fixes R11's VGPR=36 depth-2 global-load serialization.
template <int K, bool HIN>
__global__ __launch_bounds__(256, 2) void mm_k(const void* __restrict__ Xv,
                                               const float* __restrict__ W,
                                               float2* __restrict__ Y) {
    constexpr int RS = K + 4;            // LDS row stride (floats); keeps 16B align
    __shared__ float Xs[64 * RS];
    __shared__ float Ws[K * 64];
    const int t = threadIdx.x;
    const int n0 = blockIdx.x * 64;

    // stage W: K*16 float4, coalesced
    {
        const float4* Wg = (const float4*)W;
        for (int g2 = t; g2 < K * 16; g2 += 256) {
            int row = g2 >> 4, c4 = g2 & 15;
            *(float4*)&Ws[row * 64 + c4 * 4] = Wg[g2];
        }
    }
    // stage X tile (clamped rows for the tail block)
    if (HIN) {
        const float4* Xg = (const float4*)Xv;      // 8 halves per float4
        for (int g2 = t; g2 < 64 * (K / 8); g2 += 256) {
            int row = g2 / (K / 8), c8 = g2 % (K / 8);
            int rr = n0 + row; if (rr >= NN) rr = NN - 1;
            f8 v = h16_to_f8(Xg[(size_t)rr * (K / 8) + c8]);
            float* dp = &Xs[row * RS + c8 * 8];
#pragma unroll
            for (int j = 0; j < 8; ++j) dp[j] = v.v[j];
        }
    } else {
        const float4* Xg = (const float4*)Xv;
        for (int g2 = t; g2 < 64 * (K / 4); g2 += 256) {
            int row = g2 / (K / 4), c4 = g2 % (K / 4);
            int rr = n0 + row; if (rr >= NN) rr = NN - 1;
            *(float4*)&Xs[row * RS + c4 * 4] = Xg[(size_t)rr * (K / 4) + c4];
        }
    }
    __syncthreads();

    const int r0 = (t >> 4) << 2;
    const int c0 = (t & 15) << 2;
    float acc[4][4];
#pragma unroll
    for (int j = 0; j < 4; ++j)
#pragma unroll
        for (int c = 0; c < 4; ++c) acc[j][c] = 0.f;

#pragma unroll 8
    for (int kq = 0; kq < K / 4; ++kq) {
        float4 xv[4];
#pragma unroll
        for (int j = 0; j < 4; ++j)
            xv[j] = *(const float4*)&Xs[(r0 + j) * RS + kq * 4];
        float4 wv[4];
#pragma unroll
        for (int i = 0; i < 4; ++i)
            wv[i] = *(const float4*)&Ws[(kq * 4 + i) * 64 + c0];
#pragma unroll
        for (int j = 0; j < 4; ++j) {
            acc[j][0] = fmaf(xv[j].x, wv[0].x, acc[j][0]);
            acc[j][1] = fmaf(xv[j].x, wv[0].y, acc[j][1]);
            acc[j][2] = fmaf(xv[j].x, wv[0].z, acc[j][2]);
            acc[j][3] = fmaf(xv[j].x, wv[0].w, acc[j][3]);
            acc[j][0] = fmaf(xv[j].y, wv[1].x, acc[j][0]);
            acc[j][1] = fmaf(xv[j].y, wv[1].y, acc[j][1]);
            acc[j][2] = fmaf(xv[j].y, wv[1].z, acc[j][2]);
            acc[j][3] = fmaf(xv[j].y, wv[1].w, acc[j][3]);
            acc[j][0] = fmaf(xv[j].z, wv[2].x, acc[j][0]);
            acc[j][1] = fmaf(xv[j].z, wv[2].y, acc[j][1]);
            acc[j][2] = fmaf(xv[j].z, wv[2].z, acc[j][2]);
            acc[j][3] = fmaf(xv[j].z, wv[2].w, acc[j][3]);
            acc[j][0] = fmaf(xv[j].w, wv[3].x, acc[j][0]);
            acc[j][1] = fmaf(xv[j].w, wv[3].y, acc[j][1]);
            acc[j][2] = fmaf(xv[j].w, wv[3].z, acc[j][2]);
            acc[j][3] = fmaf(xv[j].w, wv[3].w, acc[j][3]);
        }
    }

#pragma unroll
    for (int j = 0; j < 4; ++j) {
        int rr = n0 + r0 + j;
        if (rr < NN)
            Y[(size_t)rr * 16 + (t & 15)] =
                f4_to_h8(make_float4(acc[j][0], acc[j][1], acc[j][2], acc[j][3]));
    }
}

// ---- fp16 propagate core: software-pipelined, sched_barrier-pinned --------
__device__ __forceinline__ void prop_gather8(const float4* __restrict__ X4,
                                             const int2* __restrict__ E,
                                             int e0, int e1, int fl, int slotbase,
                                             float acc[8], float acc2[8]) {
    if (e0 >= e1) return;
    int2 d0 = E[e0 + fl];
    int srcs[8]; float ws[8];
#pragma unroll
    for (int i = 0; i < 8; ++i) {
        srcs[i] = __shfl(d0.x, slotbase + i, 64);
        ws[i]   = __shfl(__int_as_float(d0.y), slotbase + i, 64);
    }
    int2 d1;
    if (e0 + 8 < e1) d1 = E[e0 + 8 + fl];
    float4 rr[8];
#pragma unroll
    for (int i = 0; i < 8; ++i) rr[i] = X4[(size_t)srcs[i] * 8 + fl];

    for (int e = e0; e < e1; ) {
        int en = e + 8;
        float4 rn[8]; float wn[8];
        if (en < e1) {
            int sn[8];
#pragma unroll
            for (int i = 0; i < 8; ++i) {
                sn[i] = __shfl(d1.x, slotbase + i, 64);
                wn[i] = __shfl(__int_as_float(d1.y), slotbase + i, 64);
            }
            if (en + 8 < e1) d1 = E[en + 8 + fl];
#pragma unroll
            for (int i = 0; i < 8; ++i) rn[i] = X4[(size_t)sn[i] * 8 + fl];
        }
        __builtin_amdgcn_sched_barrier(0);
#pragma unroll
        for (int i = 0; i < 8; ++i) {
            f8 x = h16_to_f8(rr[i]);
            float* a = (i & 1) ? acc2 : acc;
#pragma unroll
            for (int j = 0; j < 8; ++j)
                a[j] = fmaf(ws[i], x.v[j], a[j]);
        }
        e = en;
        if (e < e1) {
#pragma unroll
            for (int i = 0; i < 8; ++i) { rr[i] = rn[i]; ws[i] = wn[i]; }
        }
    }
}

// ---------------- propagate + bias + BN-stats (fp16 in, fp16 out) ----------
__global__ __launch_bounds__(256, 2) void prop_stats_k(
        const float4* __restrict__ X4, const int* __restrict__ offs,
        const int2* __restrict__ edge2, const float* __restrict__ dinv,
        const float* __restrict__ bias, float4* __restrict__ Y4,
        float* __restrict__ stats) {
    const int lane = threadIdx.x & 63;
    const int wave = threadIdx.x >> 6;
    const int slot = lane >> 3;
    const int fl = lane & 7;
    const int slotbase = lane & 56;
    const int wid = blockIdx.x * 4 + wave;
    const int nw = gridDim.x * 4;

    float bias8[8];
    {
        float4 b0 = ((const float4*)bias)[fl * 2];
        float4 b1 = ((const float4*)bias)[fl * 2 + 1];
        bias8[0] = b0.x; bias8[1] = b0.y; bias8[2] = b0.z; bias8[3] = b0.w;
        bias8[4] = b1.x; bias8[5] = b1.y; bias8[6] = b1.z; bias8[7] = b1.w;
    }

    float s1[8], s2[8];
#pragma unroll
    for (int j = 0; j < 8; ++j) { s1[j] = 0.f; s2[j] = 0.f; }

    for (int g = wid; g < NGRP; g += nw) {
        int n = g * 8 + slot;
        float dn = dinv[n];
        float dd = dn * dn;
        f8 self = h16_to_f8(X4[(size_t)n * 8 + fl]);
        float acc[8], acc2[8];
#pragma unroll
        for (int j = 0; j < 8; ++j) { acc[j] = dd * self.v[j]; acc2[j] = 0.f; }
        int e0 = offs[n], e1 = offs[n + 1];
        prop_gather8(X4, edge2, e0, e1, fl, slotbase, acc, acc2);
        f8 o;
#pragma unroll
        for (int j = 0; j < 8; ++j) {
            float a = acc[j] + acc2[j] + bias8[j];
            o.v[j] = a;
            s1[j] += a;
            s2[j] = fmaf(a, a, s2[j]);
        }
        Y4[(size_t)n * 8 + fl] = f8_to_h16(o);
    }

    // reduce across the 8 slots (lanes differing in bits 3,4,5)
#pragma unroll
    for (int m = 8; m <= 32; m <<= 1) {
#pragma unroll
        for (int j = 0; j < 8; ++j) {
            s1[j] += __shfl_xor(s1[j], m, 64);
            s2[j] += __shfl_xor(s2[j], m, 64);
        }
    }

    __shared__ float red[4][8][16];
    if (lane < 8) {
#pragma unroll
        for (int j = 0; j < 8; ++j) {
            red[wave][lane][j] = s1[j];
            red[wave][lane][8 + j] = s2[j];
        }
    }
    __syncthreads();
    int t = threadIdx.x;
    if (t < 128) {
        int j = t & 63;            // feature index
        int isq = t >> 6;          // 0 = sum, 1 = sumsq
        int fli = j >> 3, c = (j & 7) + isq * 8;
        float a = red[0][fli][c] + red[1][fli][c] + red[2][fli][c] + red[3][fli][c];
        atomicAdd(&stats[(blockIdx.x & (NSLICE - 1)) * 128 + isq * 64 + j], a);
    }
}

// ------- batchnorm + relu: fp16 in -> fp16 out; reduces 32 stat slices -----
__global__ __launch_bounds__(256) void bn_relu_k(
        const float4* __restrict__ Y4, const float* __restrict__ slices,
        const float* __restrict__ g, const float* __restrict__ be,
        float4* __restrict__ H4) {
    __shared__ float fs[128];
    int t = threadIdx.x;
    if (t < 128) {
        float s = 0.f;
#pragma unroll
        for (int k = 0; k < NSLICE; ++k) s += slices[k * 128 + t];
        fs[t] = s;
    }
    __syncthreads();
    int i = blockIdx.x * blockDim.x + t;
    if (i >= NN * 8) return;
    int fg = i & 7;                 // feats [fg*8, fg*8+8)
    const float invN = 1.f / (float)NN;
    f8 y = h16_to_f8(Y4[i]);
    float4 gv0 = ((const float4*)g)[fg * 2];
    float4 gv1 = ((const float4*)g)[fg * 2 + 1];
    float4 bv0 = ((const float4*)be)[fg * 2];
    float4 bv1 = ((const float4*)be)[fg * 2 + 1];
    float gv[8] = { gv0.x, gv0.y, gv0.z, gv0.w, gv1.x, gv1.y, gv1.z, gv1.w };
    float bv[8] = { bv0.x, bv0.y, bv0.z, bv0.w, bv1.x, bv1.y, bv1.z, bv1.w };
    f8 o;
#pragma unroll
    for (int j = 0; j < 8; ++j) {
        float m = fs[fg * 8 + j] * invN;
        float v = fs[64 + fg * 8 + j] * invN - m * m;
        float val = fmaf(gv[j] * rsqrtf(v + BN_EPS), y.v[j] - m, bv[j]);
        o.v[j] = val > 0.f ? val : 0.f;
    }
    H4[i] = f8_to_h16(o);
}

// ---------------- fp16 -> fp8 row conversion ----------------
__global__ void cvt16to8_k(const float4* __restrict__ H4, uint2* __restrict__ X8) {
    int i = blockIdx.x * blockDim.x + threadIdx.x;
    if (i >= NN * 8) return;
    f8 v = h16_to_f8(H4[i]);
    X8[i] = f_to_fp8x8(v.v);
}

// ---- fp8 APPNP: 16 nodes/wave, pipelined + sched_barrier-pinned -----------
template <bool OUT16>
__global__ __launch_bounds__(256, 2) void appnp8_k(
        const uint4* __restrict__ X8, const float4* __restrict__ H04,
        const int* __restrict__ offs, const int2* __restrict__ edge2,
        const float* __restrict__ dinv,
        uint4* __restrict__ Y8, float4* __restrict__ Y16) {
    const int lane = threadIdx.x & 63;
    const int wave = threadIdx.x >> 6;
    const int slot = lane >> 2;
    const int fl = lane & 3;
    const int quadbase = lane & 60;
    const int wid = blockIdx.x * 4 + wave;
    if (wid >= NG16) return;
    int n = wid * 16 + slot;
    float dn = dinv[n];
    float dd = dn * dn;
    float acc[16];
    {
        float self[16];
        fp8x16_to_f(X8[(size_t)n * 4 + fl], self);
#pragma unroll
        for (int j = 0; j < 16; ++j) acc[j] = dd * self[j];
    }
    int e0 = offs[n], e1 = offs[n + 1];
    if (e0 < e1) {
        int4 d = ((const int4*)(edge2 + e0))[fl];   // 2 edges per lane
        int srcs[8]; float ws[8];
#pragma unroll
        for (int k = 0; k < 8; ++k) {
            int sl = quadbase + (k >> 1);
            srcs[k] = __shfl((k & 1) ? d.z : d.x, sl, 64);
            ws[k]   = __shfl(__int_as_float((k & 1) ? d.w : d.y), sl, 64);
        }
        int4 d1;
        if (e0 + 8 < e1) d1 = ((const int4*)(edge2 + e0 + 8))[fl];
        uint4 rr[8];
#pragma unroll
        for (int k = 0; k < 8; ++k) rr[k] = X8[(size_t)srcs[k] * 4 + fl];

        for (int e = e0; e < e1; ) {
            int en = e + 8;
            uint4 rn[8]; float wn[8];
            if (en < e1) {
                int sn[8];
#pragma unroll
                for (int k = 0; k < 8; ++k) {
                    int sl = quadbase + (k >> 1);
                    sn[k] = __shfl((k & 1) ? d1.z : d1.x, sl, 64);
                    wn[k] = __shfl(__int_as_float((k & 1) ? d1.w : d1.y), sl, 64);
                }
                if (en + 8 < e1) d1 = ((const int4*)(edge2 + en + 8))[fl];
#pragma unroll
                for (int k = 0; k < 8; ++k) rn[k] = X8[(size_t)sn[k] * 4 + fl];
            }
            __builtin_amdgcn_sched_barrier(0);
#pragma unroll
            for (int k = 0; k < 8; ++k) {
                float x[16];
                fp8x16_to_f(rr[k], x);
#pragma unroll
                for (int j = 0; j < 16; ++j)
                    acc[j] = fmaf(ws[k], x[j], acc[j]);
            }
            e = en;
            if (e < e1) {
#pragma unroll
                for (int k = 0; k < 8; ++k) { rr[k] = rn[k]; ws[k] = wn[k]; }
            }
        }
    }
    // teleport: h0 fp16, feats [fl*16, fl*16+16) = float4 slots fl*2, fl*2+1
    f8 ha = h16_to_f8(H04[(size_t)n * 8 + fl * 2]);
    f8 hb = h16_to_f8(H04[(size_t)n * 8 + fl * 2 + 1]);
    float o[16];
#pragma unroll
    for (int j = 0; j < 8; ++j) {
        o[j] = fmaf(0.9f, acc[j], 0.1f * ha.v[j]);
        o[8 + j] = fmaf(0.9f, acc[8 + j], 0.1f * hb.v[j]);
    }
    if (OUT16) {
        f8 lo, hi;
#pragma unroll
        for (int j = 0; j < 8; ++j) { lo.v[j] = o[j]; hi.v[j] = o[8 + j]; }
        Y16[(size_t)n * 8 + fl * 2] = f8_to_h16(lo);
        Y16[(size_t)n * 8 + fl * 2 + 1] = f8_to_h16(hi);
    } else {
        Y8[(size_t)n * 4 + fl] = f_to_fp8x16(o);
    }
}

// ---------------- FC + log_softmax (fp16 in, fp32 out) ----------------
__global__ __launch_bounds__(256) void final_k(const float2* __restrict__ H2,
                                               const float* __restrict__ Wfc,
                                               const float* __restrict__ bfc,
                                               float* __restrict__ out) {
    const int t = threadIdx.x;
    const int n0 = blockIdx.x * 64;
    const int r0 = (t >> 4) << 2;
    const int c0 = (t & 15) << 2;

    int r[4];
#pragma unroll
    for (int j = 0; j < 4; ++j) {
        int rr = n0 + r0 + j;
        r[j] = rr < NN ? rr : NN - 1;
    }
    const float2* Xr[4];
#pragma unroll
    for (int j = 0; j < 4; ++j) Xr[j] = H2 + (size_t)r[j] * 16;

    float4 bf = *(const float4*)(bfc + c0);
    float acc[4][4];
#pragma unroll
    for (int j = 0; j < 4; ++j) {
        acc[j][0] = bf.x; acc[j][1] = bf.y; acc[j][2] = bf.z; acc[j][3] = bf.w;
    }

#pragma unroll 4
    for (int kq = 0; kq < 16; ++kq) {
        float4 xv[4];
#pragma unroll
        for (int j = 0; j < 4; ++j) xv[j] = h8_to_f4(Xr[j][kq]);
        float4 wv[4];
#pragma unroll
        for (int i = 0; i < 4; ++i)
            wv[i] = *(const float4*)(Wfc + (size_t)(kq * 4 + i) * 64 + c0);
#pragma unroll
        for (int j = 0; j < 4; ++j) {
            acc[j][0] = fmaf(xv[j].x, wv[0].x, acc[j][0]);
            acc[j][1] = fmaf(xv[j].x, wv[0].y, acc[j][1]);
            acc[j][2] = fmaf(xv[j].x, wv[0].z, acc[j][2]);
            acc[j][3] = fmaf(xv[j].x, wv[0].w, acc[j][3]);
            acc[j][0] = fmaf(xv[j].y, wv[1].x, acc[j][0]);
            acc[j][1] = fmaf(xv[j].y, wv[1].y, acc[j][1]);
            acc[j][2] = fmaf(xv[j].y, wv[1].z, acc[j][2]);
            acc[j][3] = fmaf(xv[j].y, wv[1].w, acc[j][3]);
            acc[j][0] = fmaf(xv[j].z, wv[2].x, acc[j][0]);
            acc[j][1] = fmaf(xv[j].z, wv[2].y, acc[j][1]);
            acc[j][2] = fmaf(xv[j].z, wv[2].z, acc[j][2]);
            acc[j][3] = fmaf(xv[j].z, wv[2].w, acc[j][3]);
            acc[j][0] = fmaf(xv[j].w, wv[3].x, acc[j][0]);
            acc[j][1] = fmaf(xv[j].w, wv[3].y, acc[j][1]);
            acc[j][2] = fmaf(xv[j].w, wv[3].z, acc[j][2]);
            acc[j][3] = fmaf(xv[j].w, wv[3].w, acc[j][3]);
        }
    }

#pragma unroll
    for (int j = 0; j < 4; ++j) {
        float m = fmaxf(fmaxf(acc[j][0], acc[j][1]), fmaxf(acc[j][2], acc[j][3]));
#pragma unroll
        for (int d = 1; d <= 8; d <<= 1) m = fmaxf(m, __shfl_xor(m, d, 64));
        float s = expf(acc[j][0] - m) + expf(acc[j][1] - m) +
                  expf(acc[j][2] - m) + expf(acc[j][3] - m);
#pragma unroll
        for (int d = 1; d <= 8; d <<= 1) s += __shfl_xor(s, d, 64);
        float lse = m + logf(s);
        int rr = n0 + r0 + j;
        if (rr < NN)
            *(float4*)(out + (size_t)rr * 64 + c0) =
                make_float4(acc[j][0] - lse, acc[j][1] - lse,
                            acc[j][2] - lse, acc[j][3] - lse);
    }
}

// ---------------- host launch ----------------

static inline char* alignup(char* p, size_t a) {
    return (char*)(((uintptr_t)p + a - 1) & ~(uintptr_t)(a - 1));
}

extern "C" void kernel_launch(void* const* d_in, const int* in_sizes, int n_in,
                              void* d_out, int out_size, void* d_ws, size_t ws_size,
                              hipStream_t stream) {
    const float* x   = (const float*)d_in[0];
    const int*   ei  = (const int*)d_in[1];
    const float* W1  = (const float*)d_in[2];
    const float* b1  = (const float*)d_in[3];
    const float* W2  = (const float*)d_in[4];
    const float* b2  = (const float*)d_in[5];
    const float* Wx  = (const float*)d_in[6];
    const float* bx  = (const float*)d_in[7];
    const float* g1  = (const float*)d_in[8];
    const float* be1 = (const float*)d_in[9];
    const float* g2  = (const float*)d_in[10];
    const float* be2 = (const float*)d_in[11];
    const float* g3  = (const float*)d_in[12];
    const float* be3 = (const float*)d_in[13];
    const float* Wfc = (const float*)d_in[14];
    const float* bfc = (const float*)d_in[15];
    float* out = (float*)d_out;

    const int* srcA = ei;
    const int* dstA = ei + NE;

    char* p = (char*)d_ws;
    int*   deg    = (int*)p;   p += NN * 4;
    int*   cursor = (int*)p;   p += NN * 4;
    float* stats  = (float*)p; p += 4 * NSLICE * 128 * 4;   // 4 layers x 32 slices x 128
    size_t zbytes = (size_t)(p - (char*)d_ws);
    p = alignup(p, 512);
    int*   offs  = (int*)p;    p += (NN + 4) * 4;   p = alignup(p, 512);
    float* dinv  = (float*)p;  p += NN * 4;         p = alignup(p, 512);
    int*   bsum  = (int*)p;    p += 256 * 4;
    int*   bpre  = (int*)p;    p += 256 * 4;        p = alignup(p, 512);
    int2*  edge2 = (int2*)p;   p += ((size_t)NE + 8 * NN + 256) * 8; p = alignup(p, 512);
    float4* tmpH = (float4*)p; p += (size_t)NN * 64 * 2; p = alignup(p, 512);
    float4* hbH  = (float4*)p; p += (size_t)NN * 64 * 2; p = alignup(p, 512);
    float4* apH  = (float4*)p; p += (size_t)NN * 64 * 2; p = alignup(p, 512);
    float4* pbH  = (float4*)p; p += (size_t)NN * 64 * 2; p = alignup(p, 512);
    uint4*  x8a  = (uint4*)p;  p += (size_t)NN * 64;     p = alignup(p, 512);
    uint4*  x8b  = (uint4*)p;  p += (size_t)NN * 64;

    hipMemsetAsync(d_ws, 0, zbytes, stream);

    count_k<<<(NE + 255) / 256, 256, 0, stream>>>(dstA, deg);
    dinv_k<<<(NN + 255) / 256, 256, 0, stream>>>(deg, dinv);
    scan1_k<<<SCAN_B, 256, 0, stream>>>(deg, offs, bsum);
    scan2_k<<<1, 256, 0, stream>>>(bsum, bpre, offs);
    scan3_k<<<(NN + 255) / 256, 256, 0, stream>>>(offs, bpre);
    pad_k<<<(NN + 255) / 256, 256, 0, stream>>>(deg, offs, edge2);
    scatter_k<<<(NE + 255) / 256, 256, 0, stream>>>(srcA, dstA, offs, cursor, dinv, edge2);

    const int MMG = (NN + 63) / 64;          // 782
    const int PG  = (NGRP + 3) / 4;          // 1563: one octet per wave
    const int AG  = (NG16 + 3) / 4;          // 782:  one 16-group per wave
    const int BNG = (NN * 8 + 255) / 256;    // 1563
    const int SL  = NSLICE * 128;            // floats per layer slice block

    mm_k<INF_, false><<<MMG, 256, 0, stream>>>(x, W1, (float2*)tmpH);
    prop_stats_k<<<PG, 256, 0, stream>>>(tmpH, offs, edge2, dinv, b1, pbH, stats + 0 * SL);
    bn_relu_k<<<BNG, 256, 0, stream>>>(pbH, stats + 0 * SL, g1, be1, hbH);

    mm_k<HID, true><<<MMG, 256, 0, stream>>>(hbH, W2, (float2*)tmpH);
    prop_stats_k<<<PG, 256, 0, stream>>>(tmpH, offs, edge2, dinv, b2, pbH, stats + 1 * SL);
    bn_relu_k<<<BNG, 256, 0, stream>>>(pbH, stats + 1 * SL, g2, be2, hbH);

    for (int L = 0; L < 2; ++L) {
        mm_k<HID, true><<<MMG, 256, 0, stream>>>(hbH, Wx + (size_t)L * 64 * 64, (float2*)tmpH);
        prop_stats_k<<<PG, 256, 0, stream>>>(tmpH, offs, edge2, dinv, bx + (size_t)L * 64,
                                             pbH, stats + (2 + L) * SL);
        bn_relu_k<<<BNG, 256, 0, stream>>>(pbH, stats + (2 + L) * SL, g3, be3, hbH);
    }

    // APPNP in fp8: x8a <- fp8(hbH); 9 fp8->fp8 iters ping-pong; 10th -> fp16 apH
    cvt16to8_k<<<BNG, 256, 0, stream>>>(hbH, (uint2*)x8a);
    const uint4* cur8 = x8a;
    for (int it = 0; it < 9; ++it) {
        uint4* o8 = (cur8 == x8a) ? x8b : x8a;
        appnp8_k<false><<<AG, 256, 0, stream>>>(cur8, hbH, offs, edge2, dinv, o8, nullptr);
        cur8 = o8;
    }
    appnp8_k<true><<<AG, 256, 0, stream>>>(cur8, hbH, offs, edge2, dinv, nullptr, apH);

    final_k<<<MMG, 256, 0, stream>>>((const float2*)apH, Wfc, bfc, out);
}